// Round 2
// baseline (3814.311 us; speedup 1.0000x reference)
//
#include <hip/hip_runtime.h>
#include <hip/hip_bf16.h>

#define BB 128      // batch
#define TT 32       // seq
#define HH 512      // hidden = emb
#define VV 10000    // vocab
#define VPAD 10240  // vocab padded to 128
#define CFEAT 2048  // cnn features
#define MM 4096     // BB*TT

typedef __attribute__((ext_vector_type(4))) float f32x4;
typedef __attribute__((ext_vector_type(8))) short short8v;
typedef __attribute__((ext_vector_type(4))) short short4v;

__device__ __forceinline__ void gload_lds16(const void* g, void* l) {
  __builtin_amdgcn_global_load_lds(
      (const __attribute__((address_space(1))) unsigned int*)g,
      (__attribute__((address_space(3))) unsigned int*)l, 16, 0, 0);
}

__device__ __forceinline__ float fsigmoid(float x) { return 1.0f / (1.0f + __expf(-x)); }
__device__ __forceinline__ float ftanh(float x) {
  x = fminf(15.0f, fmaxf(-15.0f, x));
  float t = __expf(2.0f * x);
  return (t - 1.0f) / (t + 1.0f);
}

// ---------------------------------------------------------------------------
// Transpose fp32 [K][N] (leading dim ldin) -> bf16 [Npad][K], zero-pad n>=Nreal
// grid (Npad/32, K/32), block 256
__global__ __launch_bounds__(256)
void transpose_to_bf16(const float* __restrict__ in, int ldin, int K, int Nreal,
                       __hip_bfloat16* __restrict__ out)
{
  __shared__ float tile[32][33];
  const int tid = threadIdx.x;
  const int tx = tid & 31, ty = tid >> 5;          // ty 0..7
  const int k0 = blockIdx.y * 32;
  const int n0 = blockIdx.x * 32;
#pragma unroll
  for (int i = 0; i < 4; ++i) {
    int k = k0 + ty + i * 8;
    int n = n0 + tx;
    tile[ty + i * 8][tx] = (n < Nreal) ? in[(size_t)k * ldin + n] : 0.0f;
  }
  __syncthreads();
#pragma unroll
  for (int i = 0; i < 4; ++i) {
    int n = n0 + ty + i * 8;
    int k = k0 + tx;
    out[(size_t)n * K + k] = __float2bfloat16(tile[tx][ty + i * 8]);
  }
}

// ---------------------------------------------------------------------------
// h0 = tanh(cnn @ in_W + in_b) -> h0_state and h1_state.  grid (8,16) block 256
__global__ __launch_bounds__(256)
void h0_kernel(const float* __restrict__ cnn, const float* __restrict__ inW,
               const float* __restrict__ inb, float* __restrict__ h0,
               float* __restrict__ h1)
{
  __shared__ float xT[8][CFEAT];                   // 64 KB
  const int tid = threadIdx.x;
  const int r0 = blockIdx.y * 8;
  const int j0 = blockIdx.x * 64;
  {
    const float4* src = (const float4*)(cnn + (size_t)r0 * CFEAT);
    float4* dst = (float4*)&xT[0][0];
    for (int i = tid; i < 4096; i += 256) dst[i] = src[i];
  }
  __syncthreads();
  const int jj = tid & 63, rg = tid >> 6;
  const int j = j0 + jj;
  float a0 = 0.0f, a1 = 0.0f;
  for (int k4 = 0; k4 < CFEAT; k4 += 4) {
    f32x4 x0 = *(const f32x4*)&xT[rg * 2 + 0][k4];
    f32x4 x1 = *(const f32x4*)&xT[rg * 2 + 1][k4];
#pragma unroll
    for (int kk = 0; kk < 4; ++kk) {
      float wv = inW[(size_t)(k4 + kk) * HH + j];
      a0 += x0[kk] * wv;
      a1 += x1[kk] * wv;
    }
  }
  const float bb = inb[j];
  const int row0 = r0 + rg * 2;
  float v0 = ftanh(a0 + bb), v1 = ftanh(a1 + bb);
  h0[(size_t)(row0 + 0) * HH + j] = v0;  h1[(size_t)(row0 + 0) * HH + j] = v0;
  h0[(size_t)(row0 + 1) * HH + j] = v1;  h1[(size_t)(row0 + 1) * HH + j] = v1;
}

// ---------------------------------------------------------------------------
// Gather embedding rows -> bf16 Xe[t*128+b][512].  grid 4096, block 128
__global__ __launch_bounds__(128)
void gather_kernel(const int* __restrict__ xTok, const float* __restrict__ emb,
                   __hip_bfloat16* __restrict__ Xe)
{
  const int r = blockIdx.x;            // t*128 + b
  const int t = r >> 7, b = r & 127;
  const int tok = xTok[b * TT + t];
  float4 v = ((const float4*)(emb + (size_t)tok * HH))[threadIdx.x];
  __hip_bfloat16 o[4] = { __float2bfloat16(v.x), __float2bfloat16(v.y),
                          __float2bfloat16(v.z), __float2bfloat16(v.w) };
  *(short4v*)(Xe + (size_t)r * HH + threadIdx.x * 4) = *(const short4v*)o;
}

// ---------------------------------------------------------------------------
// bf16 MFMA GEMM, C[M][Nreal] = A[M][512] @ BT[Npad][512]^T + bias.
// m97-style: 128x128 tile, BK=32, 4 waves 2x2, global_load_lds w16.
// REMAP: row = t*128+b -> store C[(b*32+t)*Nreal + col]  (logits layout)
template<bool REMAP>
__global__ __launch_bounds__(256)
void mfma_gemm_bt(const __hip_bfloat16* __restrict__ A,
                  const __hip_bfloat16* __restrict__ BT,
                  const float* __restrict__ bias,
                  float* __restrict__ C, int Nreal)
{
  constexpr int K = 512;
  __shared__ __hip_bfloat16 ldsA[128 * 32];
  __shared__ __hip_bfloat16 ldsB[128 * 32];
  const int tid = threadIdx.x;
  const int lane = tid & 63;
  const int w = tid >> 6;
  const long m0 = (long)blockIdx.y * 128;
  const long n0 = (long)blockIdx.x * 128;
  const int wr = (w >> 1) * 64, wc = (w & 1) * 64;
  const int srow = lane >> 2;            // 0..15 within 16-row chunk
  const int skoff = (lane & 3) * 8;      // k element offset
  f32x4 acc[4][4] = {};

  for (int kt = 0; kt < K; kt += 32) {
    __syncthreads();
#pragma unroll
    for (int i = 0; i < 2; ++i) {
      int c = w + i * 4;                 // chunk 0..7 (16 rows each)
      int row = c * 16 + srow;
      gload_lds16(A + (m0 + row) * K + kt + skoff, ldsA + c * 512 + lane * 8);
      gload_lds16(BT + (n0 + row) * K + kt + skoff, ldsB + c * 512 + lane * 8);
    }
    __syncthreads();
    short8v af[4], bfv[4];
#pragma unroll
    for (int m = 0; m < 4; ++m)
      af[m] = *(const short8v*)(ldsA + (wr + m * 16 + (lane & 15)) * 32 + (lane >> 4) * 8);
#pragma unroll
    for (int n = 0; n < 4; ++n)
      bfv[n] = *(const short8v*)(ldsB + (wc + n * 16 + (lane & 15)) * 32 + (lane >> 4) * 8);
#pragma unroll
    for (int m = 0; m < 4; ++m)
#pragma unroll
      for (int n = 0; n < 4; ++n)
        acc[m][n] = __builtin_amdgcn_mfma_f32_16x16x32_bf16(af[m], bfv[n], acc[m][n], 0, 0, 0);
  }

#pragma unroll
  for (int m = 0; m < 4; ++m) {
#pragma unroll
    for (int n = 0; n < 4; ++n) {
      int col = (int)n0 + wc + n * 16 + (lane & 15);
      if (col < Nreal) {
        float bv = bias[col];
#pragma unroll
        for (int q = 0; q < 4; ++q) {
          long row = m0 + wr + m * 16 + (lane >> 4) * 4 + q;
          float v = acc[m][n][q] + bv;
          if (REMAP) {
            long t = row >> 7, b = row & 127;
            C[(b * TT + t) * (long)Nreal + col] = v;
          } else {
            C[row * (long)Nreal + col] = v;
          }
        }
      }
    }
  }
}

// ---------------------------------------------------------------------------
// GRU layer 0, stage 1: u0 = sig(preU + h@Wu_h), rh0 = sig(preR + h@Wr_h)*h
// grid (8,8,2) block 256
__global__ __launch_bounds__(256)
void gru0_ur_kernel(const float* __restrict__ h,
                    const float* __restrict__ Wu, const float* __restrict__ Wr,
                    const float* __restrict__ preU, const float* __restrict__ preR,
                    float* __restrict__ u_out, float* __restrict__ rh_out, int t)
{
  __shared__ float hT[16][512];
  const int tid = threadIdx.x;
  const int r0 = blockIdx.y * 16;
  const int j0 = blockIdx.x * 64;
  const bool isU = (blockIdx.z == 0);
  const float* W = (isU ? Wu : Wr) + (size_t)HH * HH;   // h-part rows 512..1023
  const float* pre = isU ? preU : preR;
  {
    const float4* src = (const float4*)(h + (size_t)r0 * HH);
    float4* dst = (float4*)&hT[0][0];
    for (int i = tid; i < 2048; i += 256) dst[i] = src[i];
  }
  __syncthreads();
  const int jj = tid & 63, rg = tid >> 6;
  const int j = j0 + jj;
  f32x4 acc = {0.0f, 0.0f, 0.0f, 0.0f};
  for (int k4 = 0; k4 < 512; k4 += 4) {
    f32x4 h0v = *(const f32x4*)&hT[rg * 4 + 0][k4];
    f32x4 h1v = *(const f32x4*)&hT[rg * 4 + 1][k4];
    f32x4 h2v = *(const f32x4*)&hT[rg * 4 + 2][k4];
    f32x4 h3v = *(const f32x4*)&hT[rg * 4 + 3][k4];
#pragma unroll
    for (int kk = 0; kk < 4; ++kk) {
      float wv = W[(size_t)(k4 + kk) * HH + j];
      acc[0] += h0v[kk] * wv; acc[1] += h1v[kk] * wv;
      acc[2] += h2v[kk] * wv; acc[3] += h3v[kk] * wv;
    }
  }
#pragma unroll
  for (int q = 0; q < 4; ++q) {
    int row = r0 + rg * 4 + q;
    float pa = pre[(size_t)(t * BB + row) * HH + j];
    float s = fsigmoid(acc[q] + pa);
    if (isU) u_out[(size_t)row * HH + j] = s;
    else     rh_out[(size_t)row * HH + j] = s * hT[rg * 4 + q][j];
  }
}

// GRU layer 0, stage 2: c0 = tanh(preC + rh@Wc_h); h = u*h + (1-u)*c0 (in place)
// grid (8,8) block 256
__global__ __launch_bounds__(256)
void gru0_ch_kernel(float* __restrict__ h,
                    const float* __restrict__ Wc, const float* __restrict__ preC,
                    const float* __restrict__ u_in, const float* __restrict__ rh_in,
                    int t)
{
  __shared__ float rT[16][512];
  const int tid = threadIdx.x;
  const int r0 = blockIdx.y * 16;
  const int j0 = blockIdx.x * 64;
  const float* W = Wc + (size_t)HH * HH;
  {
    const float4* src = (const float4*)(rh_in + (size_t)r0 * HH);
    float4* dst = (float4*)&rT[0][0];
    for (int i = tid; i < 2048; i += 256) dst[i] = src[i];
  }
  __syncthreads();
  const int jj = tid & 63, rg = tid >> 6;
  const int j = j0 + jj;
  f32x4 acc = {0.0f, 0.0f, 0.0f, 0.0f};
  for (int k4 = 0; k4 < 512; k4 += 4) {
    f32x4 r0v = *(const f32x4*)&rT[rg * 4 + 0][k4];
    f32x4 r1v = *(const f32x4*)&rT[rg * 4 + 1][k4];
    f32x4 r2v = *(const f32x4*)&rT[rg * 4 + 2][k4];
    f32x4 r3v = *(const f32x4*)&rT[rg * 4 + 3][k4];
#pragma unroll
    for (int kk = 0; kk < 4; ++kk) {
      float wv = W[(size_t)(k4 + kk) * HH + j];
      acc[0] += r0v[kk] * wv; acc[1] += r1v[kk] * wv;
      acc[2] += r2v[kk] * wv; acc[3] += r3v[kk] * wv;
    }
  }
#pragma unroll
  for (int q = 0; q < 4; ++q) {
    int row = r0 + rg * 4 + q;
    size_t idx = (size_t)row * HH + j;
    float c = ftanh(acc[q] + preC[(size_t)(t * BB + row) * HH + j]);
    float u = u_in[idx];
    float hv = h[idx];
    h[idx] = u * hv + (1.0f - u) * c;
  }
}

// GRU layer 1, stage 1: cat=[x(=h0new), h1]; u1/rh1.  grid (8,8,2) block 256
__global__ __launch_bounds__(256)
void gru1_ur_kernel(const float* __restrict__ x, const float* __restrict__ h,
                    const float* __restrict__ Wu, const float* __restrict__ Wr,
                    const float* __restrict__ bu, const float* __restrict__ br,
                    float* __restrict__ u_out, float* __restrict__ rh_out)
{
  __shared__ float catT[16][1024];                 // 64 KB
  const int tid = threadIdx.x;
  const int r0 = blockIdx.y * 16;
  const int j0 = blockIdx.x * 64;
  const bool isU = (blockIdx.z == 0);
  const float* W = isU ? Wu : Wr;
  const float* bias = isU ? bu : br;
  {
    const float4* xs = (const float4*)(x + (size_t)r0 * HH);
    const float4* hs = (const float4*)(h + (size_t)r0 * HH);
    for (int i = tid; i < 2048; i += 256) {
      int r = i >> 7, c = i & 127;
      float4* rowp = (float4*)&catT[r][0];
      rowp[c] = xs[i];
      rowp[128 + c] = hs[i];
    }
  }
  __syncthreads();
  const int jj = tid & 63, rg = tid >> 6;
  const int j = j0 + jj;
  f32x4 acc = {0.0f, 0.0f, 0.0f, 0.0f};
  for (int k4 = 0; k4 < 1024; k4 += 4) {
    f32x4 c0v = *(const f32x4*)&catT[rg * 4 + 0][k4];
    f32x4 c1v = *(const f32x4*)&catT[rg * 4 + 1][k4];
    f32x4 c2v = *(const f32x4*)&catT[rg * 4 + 2][k4];
    f32x4 c3v = *(const f32x4*)&catT[rg * 4 + 3][k4];
#pragma unroll
    for (int kk = 0; kk < 4; ++kk) {
      float wv = W[(size_t)(k4 + kk) * HH + j];
      acc[0] += c0v[kk] * wv; acc[1] += c1v[kk] * wv;
      acc[2] += c2v[kk] * wv; acc[3] += c3v[kk] * wv;
    }
  }
  const float bb = bias[j];
#pragma unroll
  for (int q = 0; q < 4; ++q) {
    int row = r0 + rg * 4 + q;
    float s = fsigmoid(acc[q] + bb);
    if (isU) u_out[(size_t)row * HH + j] = s;
    else     rh_out[(size_t)row * HH + j] = s * catT[rg * 4 + q][512 + j];
  }
}

// GRU layer 1, stage 2: cat=[x, rh1]; c1; h1 = u*h1+(1-u)*c1; emit bf16 H1b[t]
// grid (8,8) block 256
__global__ __launch_bounds__(256)
void gru1_ch_kernel(const float* __restrict__ x, float* __restrict__ h,
                    const float* __restrict__ Wc, const float* __restrict__ bc,
                    const float* __restrict__ u_in, const float* __restrict__ rh_in,
                    __hip_bfloat16* __restrict__ H1b, int t)
{
  __shared__ float catT[16][1024];
  const int tid = threadIdx.x;
  const int r0 = blockIdx.y * 16;
  const int j0 = blockIdx.x * 64;
  {
    const float4* xs = (const float4*)(x + (size_t)r0 * HH);
    const float4* rs = (const float4*)(rh_in + (size_t)r0 * HH);
    for (int i = tid; i < 2048; i += 256) {
      int r = i >> 7, c = i & 127;
      float4* rowp = (float4*)&catT[r][0];
      rowp[c] = xs[i];
      rowp[128 + c] = rs[i];
    }
  }
  __syncthreads();
  const int jj = tid & 63, rg = tid >> 6;
  const int j = j0 + jj;
  f32x4 acc = {0.0f, 0.0f, 0.0f, 0.0f};
  for (int k4 = 0; k4 < 1024; k4 += 4) {
    f32x4 c0v = *(const f32x4*)&catT[rg * 4 + 0][k4];
    f32x4 c1v = *(const f32x4*)&catT[rg * 4 + 1][k4];
    f32x4 c2v = *(const f32x4*)&catT[rg * 4 + 2][k4];
    f32x4 c3v = *(const f32x4*)&catT[rg * 4 + 3][k4];
#pragma unroll
    for (int kk = 0; kk < 4; ++kk) {
      float wv = Wc[(size_t)(k4 + kk) * HH + j];
      acc[0] += c0v[kk] * wv; acc[1] += c1v[kk] * wv;
      acc[2] += c2v[kk] * wv; acc[3] += c3v[kk] * wv;
    }
  }
  const float bb = bc[j];
#pragma unroll
  for (int q = 0; q < 4; ++q) {
    int row = r0 + rg * 4 + q;
    size_t idx = (size_t)row * HH + j;
    float c = ftanh(acc[q] + bb);
    float u = u_in[idx];
    float hv = h[idx];
    float hn = u * hv + (1.0f - u) * c;
    h[idx] = hn;
    H1b[(size_t)(t * BB + row) * HH + j] = __float2bfloat16(hn);
  }
}

// final_state = [h0, h1] appended after logits.  grid 512, block 256
__global__ __launch_bounds__(256)
void final_copy_kernel(const float* __restrict__ h0, const float* __restrict__ h1,
                       float* __restrict__ out)
{
  int i = blockIdx.x * 256 + threadIdx.x;          // 0..131071
  out[(size_t)BB * TT * VV + i] = (i < BB * HH) ? h0[i] : h1[i - BB * HH];
}

// ---------------------------------------------------------------------------
extern "C" void kernel_launch(void* const* d_in, const int* in_sizes, int n_in,
                              void* d_out, int out_size, void* d_ws, size_t ws_size,
                              hipStream_t stream)
{
  (void)in_sizes; (void)n_in; (void)out_size; (void)ws_size;
  const float* cnn  = (const float*)d_in[0];
  const int*   xTok = (const int*)d_in[1];
  const float* emb  = (const float*)d_in[2];
  const float* inW  = (const float*)d_in[3];
  const float* inb  = (const float*)d_in[4];
  const float* Wu0  = (const float*)d_in[5];
  const float* bu0  = (const float*)d_in[6];
  const float* Wr0  = (const float*)d_in[7];
  const float* br0  = (const float*)d_in[8];
  const float* Wc0  = (const float*)d_in[9];
  const float* bc0  = (const float*)d_in[10];
  const float* Wu1  = (const float*)d_in[11];
  const float* bu1  = (const float*)d_in[12];
  const float* Wr1  = (const float*)d_in[13];
  const float* br1  = (const float*)d_in[14];
  const float* Wc1  = (const float*)d_in[15];
  const float* bc1  = (const float*)d_in[16];
  const float* outW = (const float*)d_in[17];
  const float* outb = (const float*)d_in[18];
  float* out = (float*)d_out;

  // workspace layout (~21.6 MB)
  char* ws = (char*)d_ws;
  size_t off = 0;
  auto alloc = [&](size_t bytes) { void* p = ws + off; off += (bytes + 255) & ~(size_t)255; return p; };
  __hip_bfloat16* WoT = (__hip_bfloat16*)alloc((size_t)VPAD * HH * 2);
  __hip_bfloat16* WTu = (__hip_bfloat16*)alloc((size_t)HH * HH * 2);
  __hip_bfloat16* WTr = (__hip_bfloat16*)alloc((size_t)HH * HH * 2);
  __hip_bfloat16* WTc = (__hip_bfloat16*)alloc((size_t)HH * HH * 2);
  __hip_bfloat16* Xe  = (__hip_bfloat16*)alloc((size_t)MM * HH * 2);
  __hip_bfloat16* H1b = (__hip_bfloat16*)alloc((size_t)MM * HH * 2);
  float* h0s  = (float*)alloc((size_t)BB * HH * 4);
  float* h1s  = (float*)alloc((size_t)BB * HH * 4);
  float* u0b  = (float*)alloc((size_t)BB * HH * 4);
  float* rh0b = (float*)alloc((size_t)BB * HH * 4);
  float* u1b  = (float*)alloc((size_t)BB * HH * 4);
  float* rh1b = (float*)alloc((size_t)BB * HH * 4);
  // x-projection preactivations live in d_out's logits region (24 MB << 164 MB;
  // fully consumed before the logits GEMM overwrites the region).
  float* preU = out;
  float* preR = out + (size_t)MM * HH;
  float* preC = out + (size_t)2 * MM * HH;

  // 1. weight transposes -> bf16 (B^T layout for MFMA GEMMs)
  transpose_to_bf16<<<dim3(VPAD / 32, HH / 32), 256, 0, stream>>>(outW, VV, HH, VV, WoT);
  transpose_to_bf16<<<dim3(HH / 32, HH / 32), 256, 0, stream>>>(Wu0, HH, HH, HH, WTu);
  transpose_to_bf16<<<dim3(HH / 32, HH / 32), 256, 0, stream>>>(Wr0, HH, HH, HH, WTr);
  transpose_to_bf16<<<dim3(HH / 32, HH / 32), 256, 0, stream>>>(Wc0, HH, HH, HH, WTc);

  // 2. initial hidden state (both layers)
  h0_kernel<<<dim3(8, 16), 256, 0, stream>>>(cnn, inW, inb, h0s, h1s);

  // 3. embedding gather (bf16)
  gather_kernel<<<MM, 128, 0, stream>>>(xTok, emb, Xe);

  // 4. layer-0 x-projections for all timesteps (bf16 MFMA, bias folded)
  mfma_gemm_bt<false><<<dim3(HH / 128, MM / 128), 256, 0, stream>>>(Xe, WTu, bu0, preU, HH);
  mfma_gemm_bt<false><<<dim3(HH / 128, MM / 128), 256, 0, stream>>>(Xe, WTr, br0, preR, HH);
  mfma_gemm_bt<false><<<dim3(HH / 128, MM / 128), 256, 0, stream>>>(Xe, WTc, bc0, preC, HH);

  // 5. sequential GRU scan (fp32)
  for (int t = 0; t < TT; ++t) {
    gru0_ur_kernel<<<dim3(8, 8, 2), 256, 0, stream>>>(h0s, Wu0, Wr0, preU, preR, u0b, rh0b, t);
    gru0_ch_kernel<<<dim3(8, 8), 256, 0, stream>>>(h0s, Wc0, preC, u0b, rh0b, t);
    gru1_ur_kernel<<<dim3(8, 8, 2), 256, 0, stream>>>(h0s, h1s, Wu1, Wr1, bu1, br1, u1b, rh1b);
    gru1_ch_kernel<<<dim3(8, 8), 256, 0, stream>>>(h0s, h1s, Wc1, bc1, u1b, rh1b, H1b, t);
  }

  // 6. batched logits GEMM (bf16 MFMA) with (t,b)->(b,t) store remap + bias
  mfma_gemm_bt<true><<<dim3(VPAD / 128, MM / 128), 256, 0, stream>>>(H1b, WoT, outb, out, VV);

  // 7. final hidden states
  final_copy_kernel<<<512, 256, 0, stream>>>(h0s, h1s, out);
}